// Round 3
// baseline (279.537 us; speedup 1.0000x reference)
//
#include <hip/hip_runtime.h>

#define S_LEN 4096
#define D_DIM 64
#define NEG_BIG 1.0e15f
#define NC1 8          // k-chunks for stats kernel (8 tiles each)
#define NC2 8          // k-chunks for W+PV kernel
#define SSTAT (8 * 64 * NC1 * 128)          // floats: [b][qt][kc][{m,l}][64]
#define NPAD_OFF SSTAT                      // 8 floats (padded to 64)
#define PV_OFF (SSTAT + 64)                 // [b][qt][kc][64*64] floats
#define PV_SZ (8 * 64 * NC2 * 4096)
#define WS_FLOATS_NEEDED (PV_OFF + PV_SZ)
#define VSTRIDE 70     // odd word-stride (35): transpose u16 writes ~4-way not 16-way

typedef __bf16 bf16_t;
typedef bf16_t bf16x8 __attribute__((ext_vector_type(8)));
typedef bf16_t bf16x4v __attribute__((ext_vector_type(4)));
typedef bf16_t bf16x2v __attribute__((ext_vector_type(2)));
typedef float f32x4v __attribute__((ext_vector_type(4)));

// ---------------- kernel 0: per-batch non-padded key count ----------------
__global__ void npad_count(const float* __restrict__ Pg, float* __restrict__ ws)
{
    __shared__ float red[4];
    const int b = blockIdx.x;
    const int tid = threadIdx.x;
    float cnt = 0.f;
    const float* pb = Pg + (size_t)b * S_LEN;
    for (int i = tid; i < S_LEN; i += 256) cnt += 1.f - pb[i];
    #pragma unroll
    for (int off = 32; off >= 1; off >>= 1) cnt += __shfl_down(cnt, off);
    if ((tid & 63) == 0) red[tid >> 6] = cnt;
    __syncthreads();
    if (tid == 0) ws[NPAD_OFF + b] = red[0] + red[1] + red[2] + red[3];
}

// ---------------- kernel 1: partial softmax stats over a k-chunk ----------------
__global__ __launch_bounds__(256, 4)
void sdpa_stats(const float* __restrict__ Qg,
                const float* __restrict__ Kg,
                const float* __restrict__ Pg,
                float* __restrict__ ws)
{
    __shared__ __align__(16) bf16_t Ks[64][72];

    const int tid  = threadIdx.x;
    const int w    = tid >> 6;
    const int lane = tid & 63;
    const int g    = lane >> 4;
    const int c    = lane & 15;
    const int gx   = blockIdx.x;
    const int b    = gx & 7;            // batch -> XCD pinning
    const int t    = gx >> 3;
    const int kc   = t & 7;             // qt-descending launch order (heavy first)
    const int qt   = 63 - (t >> 3);
    const int q0   = qt * 64;

    const size_t soff = ((size_t)((b * 64 + qt) * NC1 + kc)) * 128;

    if (kc * 8 > qt) {      // chunk entirely future: no causal keys
        if (tid < 64) { ws[soff + tid] = -INFINITY; ws[soff + 64 + tid] = 0.f; }
        return;
    }

    // Q fragments direct from global (row 16w+c, d = 8g+j+32ks)
    bf16x8 qa[2];
    {
        const float* qrow = Qg + ((size_t)b * S_LEN + q0 + 16 * w + c) * D_DIM;
        #pragma unroll
        for (int ks = 0; ks < 2; ++ks) {
            float4 a0 = *(const float4*)(qrow + ks * 32 + 8 * g);
            float4 a1 = *(const float4*)(qrow + ks * 32 + 8 * g + 4);
            qa[ks][0]=(bf16_t)a0.x; qa[ks][1]=(bf16_t)a0.y; qa[ks][2]=(bf16_t)a0.z; qa[ks][3]=(bf16_t)a0.w;
            qa[ks][4]=(bf16_t)a1.x; qa[ks][5]=(bf16_t)a1.y; qa[ks][6]=(bf16_t)a1.z; qa[ks][7]=(bf16_t)a1.w;
        }
    }

    float m[4], l[4];
    #pragma unroll
    for (int r = 0; r < 4; ++r) { m[r] = -INFINITY; l[r] = 0.f; }
    const int qgBase = q0 + 16 * w + 4 * g;
    const int kend = min(kc * 8 + 8, qt + 1);

    float4 kp4[4];
    float  pn4[4];
    auto loadK = [&](int kt) {
        const float* src = Kg + ((size_t)b * S_LEN + (size_t)kt * 64) * D_DIM;
        #pragma unroll
        for (int i = 0; i < 4; ++i)
            kp4[i] = *(const float4*)(src + (size_t)(i * 256 + tid) * 4);
        const float* pb = Pg + (size_t)b * S_LEN + (size_t)kt * 64;
        #pragma unroll
        for (int ct = 0; ct < 4; ++ct) pn4[ct] = pb[ct * 16 + c] * (-NEG_BIG);
    };
    loadK(kc * 8);

    for (int kt = kc * 8; kt < kend; ++kt) {
        #pragma unroll
        for (int i = 0; i < 4; ++i) {
            int f4 = i * 256 + tid;
            int r  = f4 >> 4;
            int c4 = (f4 & 15) * 4;
            bf16x4v bv;
            bv[0]=(bf16_t)kp4[i].x; bv[1]=(bf16_t)kp4[i].y; bv[2]=(bf16_t)kp4[i].z; bv[3]=(bf16_t)kp4[i].w;
            *(bf16x4v*)&Ks[r][c4] = bv;
        }
        float pcur[4];
        #pragma unroll
        for (int ct = 0; ct < 4; ++ct) pcur[ct] = pn4[ct];
        if (kt + 1 < kend) loadK(kt + 1);    // prefetch next tile (T14)
        __syncthreads();

        f32x4v sc[4];
        #pragma unroll
        for (int ct = 0; ct < 4; ++ct) {
            sc[ct] = (f32x4v){0.f, 0.f, 0.f, 0.f};
            #pragma unroll
            for (int ks = 0; ks < 2; ++ks) {
                bf16x8 kb = *(const bf16x8*)&Ks[ct * 16 + c][ks * 32 + 8 * g];
                sc[ct] = __builtin_amdgcn_mfma_f32_16x16x32_bf16(qa[ks], kb, sc[ct], 0, 0, 0);
            }
        }
        const int k0 = kt * 64;
        float l4[4][4];
        #pragma unroll
        for (int ct = 0; ct < 4; ++ct) {
            int kgi = k0 + ct * 16 + c;
            #pragma unroll
            for (int r = 0; r < 4; ++r) {
                float lg = sc[ct][r] * 0.125f + pcur[ct];   // -1e15 adds exact in fp32
                if (kgi > qgBase + r) lg -= NEG_BIG;
                l4[ct][r] = lg;
            }
        }
        #pragma unroll
        for (int r = 0; r < 4; ++r) {
            float tm = fmaxf(fmaxf(l4[0][r], l4[1][r]), fmaxf(l4[2][r], l4[3][r]));
            tm = fmaxf(tm, __shfl_xor(tm, 1));
            tm = fmaxf(tm, __shfl_xor(tm, 2));
            tm = fmaxf(tm, __shfl_xor(tm, 4));
            tm = fmaxf(tm, __shfl_xor(tm, 8));
            float mnew = fmaxf(m[r], tm);
            float s = __expf(l4[0][r] - mnew) + __expf(l4[1][r] - mnew)
                    + __expf(l4[2][r] - mnew) + __expf(l4[3][r] - mnew);
            s += __shfl_xor(s, 1);
            s += __shfl_xor(s, 2);
            s += __shfl_xor(s, 4);
            s += __shfl_xor(s, 8);
            l[r] = l[r] * __expf(m[r] - mnew) + s;
            m[r] = mnew;
        }
        __syncthreads();
    }

    if (c == 0) {
        #pragma unroll
        for (int r = 0; r < 4; ++r) {
            ws[soff + 16 * w + 4 * g + r]      = m[r];
            ws[soff + 64 + 16 * w + 4 * g + r] = l[r];
        }
    }
}

// ---------------- kernel 2: W tiles + partial PV over a k-chunk ----------------
__global__ __launch_bounds__(256, 4)
void sdpa_wpv(const float* __restrict__ Qg,
              const float* __restrict__ Kg,
              const float* __restrict__ Vg,
              const float* __restrict__ Pg,
              float* __restrict__ Wg,
              float* __restrict__ ws)
{
    __shared__ __align__(16) bf16_t Ks[64][72];
    __shared__ __align__(16) bf16_t VT[64][VSTRIDE];   // VT[d][k_local]
    __shared__ __align__(16) float  Wf[64][68];
    __shared__ float Mrow[64];
    __shared__ float Lrow[64];
    __shared__ int   degS;

    const int tid  = threadIdx.x;
    const int w    = tid >> 6;
    const int lane = tid & 63;
    const int g    = lane >> 4;
    const int c    = lane & 15;
    const int gx   = blockIdx.x;
    const int b    = gx & 7;
    const int t    = gx >> 3;
    const int kc   = t & 7;
    const int qt   = 63 - (t >> 3);
    const int q0   = qt * 64;
    const int kstart = kc * 8;

    // combine partial stats for this q-tile (wave 0; waves 1-3 fall through and
    // start issuing the first K/V prefetch immediately)
    if (tid < 64) {
        const size_t sbase = ((size_t)(b * 64 + qt) * NC1) * 128;
        float M = -INFINITY;
        float mv[NC1];
        #pragma unroll
        for (int i = 0; i < NC1; ++i) {
            mv[i] = ws[sbase + (size_t)i * 128 + tid];
            M = fmaxf(M, mv[i]);
        }
        float L = 0.f;
        #pragma unroll
        for (int i = 0; i < NC1; ++i)
            L += ws[sbase + (size_t)i * 128 + 64 + tid] * __expf(mv[i] - M);
        bool deg = (M < -1.0e14f);
        if (deg) L += ws[NPAD_OFF + b];
        Mrow[tid] = M;
        Lrow[tid] = 1.f / L;
        unsigned long long bal = __ballot(deg);
        if (tid == 0) degS = (bal != 0ULL) ? 1 : 0;
    }

    float4 kp4[4], vp4[4];
    float  pn4[4];
    auto loadKV = [&](int kt) {
        const float* ksrc = Kg + ((size_t)b * S_LEN + (size_t)kt * 64) * D_DIM;
        const float* vsrc = Vg + ((size_t)b * S_LEN + (size_t)kt * 64) * D_DIM;
        #pragma unroll
        for (int i = 0; i < 4; ++i) {
            kp4[i] = *(const float4*)(ksrc + (size_t)(i * 256 + tid) * 4);
            vp4[i] = *(const float4*)(vsrc + (size_t)(i * 256 + tid) * 4);
        }
        const float* pb = Pg + (size_t)b * S_LEN + (size_t)kt * 64;
        #pragma unroll
        for (int ct = 0; ct < 4; ++ct) pn4[ct] = pb[ct * 16 + c] * (-NEG_BIG);
    };
    loadKV(kstart);      // issued by all threads; overlaps wave-0's combine loads

    // Q fragments direct from global
    bf16x8 qa[2];
    {
        const float* qrow = Qg + ((size_t)b * S_LEN + q0 + 16 * w + c) * D_DIM;
        #pragma unroll
        for (int ks = 0; ks < 2; ++ks) {
            float4 a0 = *(const float4*)(qrow + ks * 32 + 8 * g);
            float4 a1 = *(const float4*)(qrow + ks * 32 + 8 * g + 4);
            qa[ks][0]=(bf16_t)a0.x; qa[ks][1]=(bf16_t)a0.y; qa[ks][2]=(bf16_t)a0.z; qa[ks][3]=(bf16_t)a0.w;
            qa[ks][4]=(bf16_t)a1.x; qa[ks][5]=(bf16_t)a1.y; qa[ks][6]=(bf16_t)a1.z; qa[ks][7]=(bf16_t)a1.w;
        }
    }
    __syncthreads();
    const bool blockDeg = (degS != 0);

    float* wchunk = Wg + (size_t)b * S_LEN * S_LEN + (size_t)q0 * S_LEN;
    float* pvb = ws + PV_OFF + ((size_t)(b * 64 + qt) * NC2 + kc) * 4096;

    if (kstart > qt && !blockDeg) {
        // entire chunk strictly future, no degenerate rows: zeros everywhere
        const float4 z = {0.f, 0.f, 0.f, 0.f};
        for (int kt = kstart; kt < kstart + 8; ++kt) {
            float* wbase = wchunk + kt * 64;
            #pragma unroll
            for (int i = 0; i < 4; ++i) {
                int f4 = i * 256 + tid;
                int r  = f4 >> 4;
                int c4 = (f4 & 15) * 4;
                *(float4*)(wbase + (size_t)r * S_LEN + c4) = z;
            }
        }
        #pragma unroll
        for (int i = 0; i < 4; ++i) *(float4*)(pvb + (size_t)(i * 256 + tid) * 4) = z;
        return;
    }

    float m[4], linv[4];
    #pragma unroll
    for (int r = 0; r < 4; ++r) {
        m[r]    = Mrow[16 * w + 4 * g + r];
        linv[r] = Lrow[16 * w + 4 * g + r];
    }
    const int qgBase = q0 + 16 * w + 4 * g;

    f32x4v o[4];
    #pragma unroll
    for (int dt = 0; dt < 4; ++dt) o[dt] = (f32x4v){0.f, 0.f, 0.f, 0.f};

    for (int kt = kstart; kt < kstart + 8; ++kt) {
        const int k0 = kt * 64;
        float* wbase = wchunk + k0;
        const bool cur = (kt <= qt) || blockDeg;

        if (cur) {
            // stage K (vector bf16x4 writes) and V transposed (u16, ~4-way with VSTRIDE=70)
            #pragma unroll
            for (int i = 0; i < 4; ++i) {
                int f4 = i * 256 + tid;
                int r  = f4 >> 4;
                int c4 = (f4 & 15) * 4;
                bf16x4v bv;
                bv[0]=(bf16_t)kp4[i].x; bv[1]=(bf16_t)kp4[i].y; bv[2]=(bf16_t)kp4[i].z; bv[3]=(bf16_t)kp4[i].w;
                *(bf16x4v*)&Ks[r][c4] = bv;
                VT[c4 + 0][r] = (bf16_t)vp4[i].x;
                VT[c4 + 1][r] = (bf16_t)vp4[i].y;
                VT[c4 + 2][r] = (bf16_t)vp4[i].z;
                VT[c4 + 3][r] = (bf16_t)vp4[i].w;
            }
            float pcur[4];
            #pragma unroll
            for (int ct = 0; ct < 4; ++ct) pcur[ct] = pn4[ct];
            {   // prefetch next working tile
                int nxt = kt + 1;
                if (nxt < kstart + 8 && (nxt <= qt || blockDeg)) loadKV(nxt);
            }
            __syncthreads();

            f32x4v sc[4];
            #pragma unroll
            for (int ct = 0; ct < 4; ++ct) {
                sc[ct] = (f32x4v){0.f, 0.f, 0.f, 0.f};
                #pragma unroll
                for (int ks = 0; ks < 2; ++ks) {
                    bf16x8 kb = *(const bf16x8*)&Ks[ct * 16 + c][ks * 32 + 8 * g];
                    sc[ct] = __builtin_amdgcn_mfma_f32_16x16x32_bf16(qa[ks], kb, sc[ct], 0, 0, 0);
                }
            }
            #pragma unroll
            for (int ct = 0; ct < 4; ++ct) {
                int kgi = k0 + ct * 16 + c;
                #pragma unroll
                for (int r = 0; r < 4; ++r) {
                    float lg = sc[ct][r] * 0.125f + pcur[ct];
                    if (kgi > qgBase + r) lg -= NEG_BIG;
                    float wv = __expf(lg - m[r]) * linv[r];   // == exact ref weight
                    Wf[16 * w + 4 * g + r][ct * 16 + c] = wv;
                }
            }
            __syncthreads();

            // coalesced fp32 W store
            #pragma unroll
            for (int i = 0; i < 4; ++i) {
                int f4 = i * 256 + tid;
                int r  = f4 >> 4;
                int c4 = (f4 & 15) * 4;
                float4 wv = *(const float4*)&Wf[r][c4];
                *(float4*)(wbase + (size_t)r * S_LEN + c4) = wv;
            }

            // PV: A = W (from Wf, cvt->bf16), B = V^T tile (4B chunk reads)
            #pragma unroll
            for (int ks = 0; ks < 2; ++ks) {
                float4 f0 = *(const float4*)&Wf[16 * w + c][ks * 32 + 8 * g];
                float4 f1 = *(const float4*)&Wf[16 * w + c][ks * 32 + 8 * g + 4];
                bf16x8 wa;
                wa[0]=(bf16_t)f0.x; wa[1]=(bf16_t)f0.y; wa[2]=(bf16_t)f0.z; wa[3]=(bf16_t)f0.w;
                wa[4]=(bf16_t)f1.x; wa[5]=(bf16_t)f1.y; wa[6]=(bf16_t)f1.z; wa[7]=(bf16_t)f1.w;
                #pragma unroll
                for (int dt = 0; dt < 4; ++dt) {
                    bf16x8 vb;
                    #pragma unroll
                    for (int p = 0; p < 4; ++p)
                        ((bf16x2v*)&vb)[p] = *(const bf16x2v*)&VT[dt * 16 + c][ks * 32 + 8 * g + 2 * p];
                    o[dt] = __builtin_amdgcn_mfma_f32_16x16x32_bf16(wa, vb, o[dt], 0, 0, 0);
                }
            }
            __syncthreads();
        } else {
            // strictly-future tile, no degenerate rows: weights exactly 0
            const float4 z = {0.f, 0.f, 0.f, 0.f};
            #pragma unroll
            for (int i = 0; i < 4; ++i) {
                int f4 = i * 256 + tid;
                int r  = f4 >> 4;
                int c4 = (f4 & 15) * 4;
                *(float4*)(wbase + (size_t)r * S_LEN + c4) = z;
            }
        }
    }

    #pragma unroll
    for (int dt = 0; dt < 4; ++dt)
        #pragma unroll
        for (int r = 0; r < 4; ++r)
            pvb[(size_t)(16 * w + 4 * g + r) * 64 + dt * 16 + c] = o[dt][r];
}

// ---------------- kernel 3: reduce PV partials -> context ----------------
__global__ void pv_reduce(const float* __restrict__ ws, float* __restrict__ Og)
{
    const size_t i = (size_t)blockIdx.x * 256 + threadIdx.x;   // 0 .. 2M-1
    const size_t bq = i >> 12;                                  // b*64 + qt
    const size_t lo = i & 4095;                                 // row*64 + d
    const float* p = ws + PV_OFF + bq * NC2 * 4096 + lo;
    float s = 0.f;
    #pragma unroll
    for (int kc2 = 0; kc2 < NC2; ++kc2) s += p[(size_t)kc2 * 4096];
    Og[i] = s;
}

// ---------------- fallback: monolithic kernel (used only if ws too small) ----------------
__global__ __launch_bounds__(256, 2)
void sdpa_fused(const float* __restrict__ Qg,
                const float* __restrict__ Kg,
                const float* __restrict__ Vg,
                const float* __restrict__ Pg,
                float* __restrict__ Og,
                float* __restrict__ Wg)
{
    __shared__ __align__(16) bf16_t Qs[64][72];
    __shared__ __align__(16) bf16_t Ks[64][72];
    __shared__ __align__(16) bf16_t VT[64][72];
    __shared__ __align__(16) float  Wf[64][68];
    __shared__ float pads[64];
    __shared__ float red[4];
    __shared__ int   anyDeg;

    const int tid  = threadIdx.x;
    const int w    = tid >> 6;
    const int lane = tid & 63;
    const int g    = lane >> 4;
    const int c    = lane & 15;
    const int b    = blockIdx.x & 7;
    const int qt   = 63 - (blockIdx.x >> 3);
    const int q0   = qt * 64;

    if (tid == 0) anyDeg = 0;

    {
        const float* src = Qg + ((size_t)b * S_LEN + q0) * D_DIM;
        #pragma unroll
        for (int i = 0; i < 4; ++i) {
            int f4 = i * 256 + tid;
            int r  = f4 >> 4;
            int c4 = (f4 & 15) * 4;
            float4 v4 = *(const float4*)(src + (size_t)f4 * 4);
            bf16x4v bv;
            bv[0]=(bf16_t)v4.x; bv[1]=(bf16_t)v4.y; bv[2]=(bf16_t)v4.z; bv[3]=(bf16_t)v4.w;
            *(bf16x4v*)&Qs[r][c4] = bv;
        }
    }
    __syncthreads();

    bf16x8 qa[2];
    {
        int row = 16 * w + c;
        #pragma unroll
        for (int ks = 0; ks < 2; ++ks)
            qa[ks] = *(const bf16x8*)&Qs[row][ks * 32 + 8 * g];
    }

    float m[4], l[4];
    #pragma unroll
    for (int r = 0; r < 4; ++r) { m[r] = -INFINITY; l[r] = 0.f; }
    const int qgBase = q0 + 16 * w + 4 * g;

    for (int kt = 0; kt <= qt; ++kt) {
        const int k0 = kt * 64;
        {
            const float* src = Kg + ((size_t)b * S_LEN + k0) * D_DIM;
            #pragma unroll
            for (int i = 0; i < 4; ++i) {
                int f4 = i * 256 + tid;
                int r  = f4 >> 4;
                int c4 = (f4 & 15) * 4;
                float4 v4 = *(const float4*)(src + (size_t)f4 * 4);
                bf16x4v bv;
                bv[0]=(bf16_t)v4.x; bv[1]=(bf16_t)v4.y; bv[2]=(bf16_t)v4.z; bv[3]=(bf16_t)v4.w;
                *(bf16x4v*)&Ks[r][c4] = bv;
            }
            if (tid < 64) pads[tid] = Pg[(size_t)b * S_LEN + k0 + tid] * (-NEG_BIG);
        }
        __syncthreads();

        f32x4v sc[4];
        #pragma unroll
        for (int ct = 0; ct < 4; ++ct) {
            sc[ct] = (f32x4v){0.f, 0.f, 0.f, 0.f};
            #pragma unroll
            for (int ks = 0; ks < 2; ++ks) {
                bf16x8 kb = *(const bf16x8*)&Ks[ct * 16 + c][ks * 32 + 8 * g];
                sc[ct] = __builtin_amdgcn_mfma_f32_16x16x32_bf16(qa[ks], kb, sc[ct], 0, 0, 0);
            }
        }
        float l4[4][4];
        #pragma unroll
        for (int ct = 0; ct < 4; ++ct) {
            float pn  = pads[ct * 16 + c];
            int   kgi = k0 + ct * 16 + c;
            #pragma unroll
            for (int r = 0; r < 4; ++r) {
                float lg = sc[ct][r] * 0.125f + pn;
                if (kgi > qgBase + r) lg -= NEG_BIG;
                l4[ct][r] = lg;
            }
        }
        #pragma unroll
        for (int r = 0; r < 4; ++r) {
            float tm = fmaxf(fmaxf(l4[0][r], l4[1][r]), fmaxf(l4[2][r], l4[3][r]));
            tm = fmaxf(tm, __shfl_xor(tm, 1));
            tm = fmaxf(tm, __shfl_xor(tm, 2));
            tm = fmaxf(tm, __shfl_xor(tm, 4));
            tm = fmaxf(tm, __shfl_xor(tm, 8));
            float mnew = fmaxf(m[r], tm);
            float s = __expf(l4[0][r] - mnew) + __expf(l4[1][r] - mnew)
                    + __expf(l4[2][r] - mnew) + __expf(l4[3][r] - mnew);
            s += __shfl_xor(s, 1);
            s += __shfl_xor(s, 2);
            s += __shfl_xor(s, 4);
            s += __shfl_xor(s, 8);
            l[r] = l[r] * __expf(m[r] - mnew) + s;
            m[r] = mnew;
        }
        __syncthreads();
    }

    {
        float cnt = 0.f;
        const float* pb = Pg + (size_t)b * S_LEN;
        for (int i = tid; i < S_LEN; i += 256) cnt += 1.f - pb[i];
        #pragma unroll
        for (int off = 32; off >= 1; off >>= 1) cnt += __shfl_down(cnt, off);
        if (lane == 0) red[w] = cnt;
    }
    __syncthreads();
    {
        float nonpad = red[0] + red[1] + red[2] + red[3];
        bool deg = false;
        #pragma unroll
        for (int r = 0; r < 4; ++r)
            if (m[r] < -1.0e14f) { l[r] += nonpad; deg = true; }
        if (deg) anyDeg = 1;
    }
    __syncthreads();
    const bool blockDeg = (anyDeg != 0);
    float linv[4];
    #pragma unroll
    for (int r = 0; r < 4; ++r) linv[r] = 1.f / l[r];

    f32x4v o[4];
    #pragma unroll
    for (int dt = 0; dt < 4; ++dt) o[dt] = (f32x4v){0.f, 0.f, 0.f, 0.f};

    for (int kt = 0; kt < 64; ++kt) {
        const int k0 = kt * 64;
        float* wbase = Wg + (size_t)b * S_LEN * S_LEN + (size_t)q0 * S_LEN + k0;

        if (kt <= qt || blockDeg) {
            const float* ksrc = Kg + ((size_t)b * S_LEN + k0) * D_DIM;
            const float* vsrc = Vg + ((size_t)b * S_LEN + k0) * D_DIM;
            #pragma unroll
            for (int i = 0; i < 4; ++i) {
                int f4 = i * 256 + tid;
                int r  = f4 >> 4;
                int c4 = (f4 & 15) * 4;
                float4 kv = *(const float4*)(ksrc + (size_t)f4 * 4);
                bf16x4v bv;
                bv[0]=(bf16_t)kv.x; bv[1]=(bf16_t)kv.y; bv[2]=(bf16_t)kv.z; bv[3]=(bf16_t)kv.w;
                *(bf16x4v*)&Ks[r][c4] = bv;
                float4 vv = *(const float4*)(vsrc + (size_t)f4 * 4);
                VT[c4 + 0][r] = (bf16_t)vv.x;
                VT[c4 + 1][r] = (bf16_t)vv.y;
                VT[c4 + 2][r] = (bf16_t)vv.z;
                VT[c4 + 3][r] = (bf16_t)vv.w;
            }
            if (tid < 64) pads[tid] = Pg[(size_t)b * S_LEN + k0 + tid] * (-NEG_BIG);
            __syncthreads();

            f32x4v sc[4];
            #pragma unroll
            for (int ct = 0; ct < 4; ++ct) {
                sc[ct] = (f32x4v){0.f, 0.f, 0.f, 0.f};
                #pragma unroll
                for (int ks = 0; ks < 2; ++ks) {
                    bf16x8 kb = *(const bf16x8*)&Ks[ct * 16 + c][ks * 32 + 8 * g];
                    sc[ct] = __builtin_amdgcn_mfma_f32_16x16x32_bf16(qa[ks], kb, sc[ct], 0, 0, 0);
                }
            }
            #pragma unroll
            for (int ct = 0; ct < 4; ++ct) {
                float pn  = pads[ct * 16 + c];
                int   kgi = k0 + ct * 16 + c;
                #pragma unroll
                for (int r = 0; r < 4; ++r) {
                    float lg = sc[ct][r] * 0.125f + pn;
                    if (kgi > qgBase + r) lg -= NEG_BIG;
                    float wv = __expf(lg - m[r]) * linv[r];
                    Wf[16 * w + 4 * g + r][ct * 16 + c] = wv;
                }
            }
            __syncthreads();

            #pragma unroll
            for (int i = 0; i < 4; ++i) {
                int f4 = i * 256 + tid;
                int r  = f4 >> 4;
                int c4 = (f4 & 15) * 4;
                float4 wv = *(const float4*)&Wf[r][c4];
                *(float4*)(wbase + (size_t)r * S_LEN + c4) = wv;
            }

            #pragma unroll
            for (int ks = 0; ks < 2; ++ks) {
                float4 f0 = *(const float4*)&Wf[16 * w + c][ks * 32 + 8 * g];
                float4 f1 = *(const float4*)&Wf[16 * w + c][ks * 32 + 8 * g + 4];
                bf16x8 wa;
                wa[0]=(bf16_t)f0.x; wa[1]=(bf16_t)f0.y; wa[2]=(bf16_t)f0.z; wa[3]=(bf16_t)f0.w;
                wa[4]=(bf16_t)f1.x; wa[5]=(bf16_t)f1.y; wa[6]=(bf16_t)f1.z; wa[7]=(bf16_t)f1.w;
                #pragma unroll
                for (int dt = 0; dt < 4; ++dt) {
                    bf16x8 vb = *(const bf16x8*)&VT[dt * 16 + c][ks * 32 + 8 * g];
                    o[dt] = __builtin_amdgcn_mfma_f32_16x16x32_bf16(wa, vb, o[dt], 0, 0, 0);
                }
            }
            __syncthreads();
        } else {
            const float4 z = {0.f, 0.f, 0.f, 0.f};
            #pragma unroll
            for (int i = 0; i < 4; ++i) {
                int f4 = i * 256 + tid;
                int r  = f4 >> 4;
                int c4 = (f4 & 15) * 4;
                *(float4*)(wbase + (size_t)r * S_LEN + c4) = z;
            }
        }
    }

    #pragma unroll
    for (int dt = 0; dt < 4; ++dt)
        #pragma unroll
        for (int r = 0; r < 4; ++r)
            Og[((size_t)b * S_LEN + (q0 + 16 * w + 4 * g + r)) * D_DIM + dt * 16 + c] = o[dt][r];
}

extern "C" void kernel_launch(void* const* d_in, const int* in_sizes, int n_in,
                              void* d_out, int out_size, void* d_ws, size_t ws_size,
                              hipStream_t stream) {
    const float* q   = (const float*)d_in[0];
    const float* k   = (const float*)d_in[1];
    const float* v   = (const float*)d_in[2];
    const float* pad = (const float*)d_in[3];

    float* out  = (float*)d_out;
    float* ctx  = out;
    float* attw = out + (size_t)8 * 4096 * 64;
    float* ws   = (float*)d_ws;

    if (ws_size >= (size_t)WS_FLOATS_NEEDED * 4) {
        hipLaunchKernelGGL(npad_count, dim3(8), dim3(256), 0, stream, pad, ws);
        hipLaunchKernelGGL(sdpa_stats, dim3(8 * 64 * NC1), dim3(256), 0, stream, q, k, pad, ws);
        hipLaunchKernelGGL(sdpa_wpv,   dim3(8 * 64 * NC2), dim3(256), 0, stream, q, k, v, pad, attw, ws);
        hipLaunchKernelGGL(pv_reduce,  dim3(8 * 4096 * 64 / 256), dim3(256), 0, stream, ws, ctx);
    } else {
        hipLaunchKernelGGL(sdpa_fused, dim3(512), dim3(256), 0, stream, q, k, v, pad, ctx, attw);
    }
}

// Round 4
// 255.527 us; speedup vs baseline: 1.0940x; 1.0940x over previous
//
#include <hip/hip_runtime.h>

#define S_LEN 4096
#define D_DIM 64
#define NEG_BIG 1.0e15f
#define NC1 8          // k-chunks for stats kernel (8 tiles each)
#define NC2 8          // k-chunks for W+PV kernel
#define SSTAT (8 * 64 * NC1 * 128)          // floats: [b][qt][kc][{m,l}][64]
#define NPAD_OFF SSTAT                      // 8 floats (padded to 64)
#define PV_OFF (SSTAT + 64)                 // [b][qt][kc][64*64] floats
#define PV_SZ (8 * 64 * NC2 * 4096)
#define WS_FLOATS_NEEDED (PV_OFF + PV_SZ)
#define VSTRIDE 70     // odd word-stride (35): transpose u16 writes ~4-way not 16-way

typedef __bf16 bf16_t;
typedef bf16_t bf16x8 __attribute__((ext_vector_type(8)));
typedef bf16_t bf16x4v __attribute__((ext_vector_type(4)));
typedef bf16_t bf16x2v __attribute__((ext_vector_type(2)));
typedef float f32x4v __attribute__((ext_vector_type(4)));

// ---------------- kernel 0: per-batch non-padded key count ----------------
__global__ void npad_count(const float* __restrict__ Pg, float* __restrict__ ws)
{
    __shared__ float red[4];
    const int b = blockIdx.x;
    const int tid = threadIdx.x;
    float cnt = 0.f;
    const float* pb = Pg + (size_t)b * S_LEN;
    for (int i = tid; i < S_LEN; i += 256) cnt += 1.f - pb[i];
    #pragma unroll
    for (int off = 32; off >= 1; off >>= 1) cnt += __shfl_down(cnt, off);
    if ((tid & 63) == 0) red[tid >> 6] = cnt;
    __syncthreads();
    if (tid == 0) ws[NPAD_OFF + b] = red[0] + red[1] + red[2] + red[3];
}

// ---------------- kernel 1: partial softmax stats over a k-chunk ----------------
__global__ __launch_bounds__(256, 2)
void sdpa_stats(const float* __restrict__ Qg,
                const float* __restrict__ Kg,
                const float* __restrict__ Pg,
                float* __restrict__ ws)
{
    __shared__ __align__(16) bf16_t Ks[64][72];
    __shared__ float pads[64];

    const int tid  = threadIdx.x;
    const int w    = tid >> 6;
    const int lane = tid & 63;
    const int g    = lane >> 4;
    const int c    = lane & 15;
    const int gx   = blockIdx.x;
    const int b    = gx & 7;            // batch -> XCD pinning
    const int t    = gx >> 3;
    const int qt   = 63 - (t & 63);     // qt descending within each kc (r2 order)
    const int kc   = t >> 6;
    const int q0   = qt * 64;

    const size_t soff = ((size_t)((b * 64 + qt) * NC1 + kc)) * 128;

    if (kc * 8 > qt) {      // chunk entirely future: no causal keys
        if (tid < 64) { ws[soff + tid] = -INFINITY; ws[soff + 64 + tid] = 0.f; }
        return;
    }

    // Q fragments direct from global (row 16w+c, d = 8g+j+32ks); L2-resident
    bf16x8 qa[2];
    {
        const float* qrow = Qg + ((size_t)b * S_LEN + q0 + 16 * w + c) * D_DIM;
        #pragma unroll
        for (int ks = 0; ks < 2; ++ks) {
            float4 a0 = *(const float4*)(qrow + ks * 32 + 8 * g);
            float4 a1 = *(const float4*)(qrow + ks * 32 + 8 * g + 4);
            qa[ks][0]=(bf16_t)a0.x; qa[ks][1]=(bf16_t)a0.y; qa[ks][2]=(bf16_t)a0.z; qa[ks][3]=(bf16_t)a0.w;
            qa[ks][4]=(bf16_t)a1.x; qa[ks][5]=(bf16_t)a1.y; qa[ks][6]=(bf16_t)a1.z; qa[ks][7]=(bf16_t)a1.w;
        }
    }

    float m[4], l[4];
    #pragma unroll
    for (int r = 0; r < 4; ++r) { m[r] = -INFINITY; l[r] = 0.f; }
    const int qgBase = q0 + 16 * w + 4 * g;
    const int kend = min(kc * 8 + 8, qt + 1);

    for (int kt = kc * 8; kt < kend; ++kt) {
        const int k0 = kt * 64;
        {
            const float* src = Kg + ((size_t)b * S_LEN + k0) * D_DIM;
            #pragma unroll
            for (int i = 0; i < 4; ++i) {
                int f4 = i * 256 + tid;
                int r  = f4 >> 4;
                int c4 = (f4 & 15) * 4;
                float4 v4 = *(const float4*)(src + (size_t)f4 * 4);
                bf16x4v bv;
                bv[0]=(bf16_t)v4.x; bv[1]=(bf16_t)v4.y; bv[2]=(bf16_t)v4.z; bv[3]=(bf16_t)v4.w;
                *(bf16x4v*)&Ks[r][c4] = bv;
            }
            if (tid < 64) pads[tid] = Pg[(size_t)b * S_LEN + k0 + tid] * (-NEG_BIG);
        }
        __syncthreads();

        f32x4v sc[4];
        #pragma unroll
        for (int ct = 0; ct < 4; ++ct) {
            sc[ct] = (f32x4v){0.f, 0.f, 0.f, 0.f};
            #pragma unroll
            for (int ks = 0; ks < 2; ++ks) {
                bf16x8 kb = *(const bf16x8*)&Ks[ct * 16 + c][ks * 32 + 8 * g];
                sc[ct] = __builtin_amdgcn_mfma_f32_16x16x32_bf16(qa[ks], kb, sc[ct], 0, 0, 0);
            }
        }
        float l4[4][4];
        #pragma unroll
        for (int ct = 0; ct < 4; ++ct) {
            float pn  = pads[ct * 16 + c];
            int   kgi = k0 + ct * 16 + c;
            #pragma unroll
            for (int r = 0; r < 4; ++r) {
                float lg = sc[ct][r] * 0.125f + pn;       // -1e15 adds exact in fp32
                if (kgi > qgBase + r) lg -= NEG_BIG;
                l4[ct][r] = lg;
            }
        }
        #pragma unroll
        for (int r = 0; r < 4; ++r) {
            float tm = fmaxf(fmaxf(l4[0][r], l4[1][r]), fmaxf(l4[2][r], l4[3][r]));
            tm = fmaxf(tm, __shfl_xor(tm, 1));
            tm = fmaxf(tm, __shfl_xor(tm, 2));
            tm = fmaxf(tm, __shfl_xor(tm, 4));
            tm = fmaxf(tm, __shfl_xor(tm, 8));
            float mnew = fmaxf(m[r], tm);
            float s = __expf(l4[0][r] - mnew) + __expf(l4[1][r] - mnew)
                    + __expf(l4[2][r] - mnew) + __expf(l4[3][r] - mnew);
            s += __shfl_xor(s, 1);
            s += __shfl_xor(s, 2);
            s += __shfl_xor(s, 4);
            s += __shfl_xor(s, 8);
            l[r] = l[r] * __expf(m[r] - mnew) + s;
            m[r] = mnew;
        }
        __syncthreads();
    }

    if (c == 0) {
        #pragma unroll
        for (int r = 0; r < 4; ++r) {
            ws[soff + 16 * w + 4 * g + r]      = m[r];
            ws[soff + 64 + 16 * w + 4 * g + r] = l[r];
        }
    }
}

// ---------------- kernel 2: W tiles + partial PV over a k-chunk ----------------
__global__ __launch_bounds__(256, 2)
void sdpa_wpv(const float* __restrict__ Qg,
              const float* __restrict__ Kg,
              const float* __restrict__ Vg,
              const float* __restrict__ Pg,
              float* __restrict__ Wg,
              float* __restrict__ ws)
{
    // LDS ~28.2 KB -> 5 blocks/CU (r2 was 45.5 KB -> 3)
    __shared__ __align__(16) bf16_t Ks[64][72];
    __shared__ __align__(16) bf16_t VT[64][VSTRIDE];   // VT[d][k_local]
    __shared__ __align__(16) bf16_t Pf[64][72];        // bf16 weights for PV A-frags
    __shared__ float pads[64];
    __shared__ float Mrow[64];
    __shared__ float Lrow[64];
    __shared__ int   degS;

    const int tid  = threadIdx.x;
    const int w    = tid >> 6;
    const int lane = tid & 63;
    const int g    = lane >> 4;
    const int c    = lane & 15;
    const int gx   = blockIdx.x;
    const int b    = gx & 7;
    const int t    = gx >> 3;
    const int qt   = 63 - (t & 63);
    const int kc   = t >> 6;
    const int q0   = qt * 64;
    const int kstart = kc * 8;

    // combine partial stats for this q-tile (wave 0, one q-row per lane)
    if (tid < 64) {
        const size_t sbase = ((size_t)(b * 64 + qt) * NC1) * 128;
        float M = -INFINITY;
        float mv[NC1];
        #pragma unroll
        for (int i = 0; i < NC1; ++i) {
            mv[i] = ws[sbase + (size_t)i * 128 + tid];
            M = fmaxf(M, mv[i]);
        }
        float L = 0.f;
        #pragma unroll
        for (int i = 0; i < NC1; ++i)
            L += ws[sbase + (size_t)i * 128 + 64 + tid] * __expf(mv[i] - M);
        bool deg = (M < -1.0e14f);
        if (deg) L += ws[NPAD_OFF + b];
        Mrow[tid] = M;
        Lrow[tid] = 1.f / L;
        unsigned long long bal = __ballot(deg);
        if (tid == 0) degS = (bal != 0ULL) ? 1 : 0;
    }
    __syncthreads();
    const bool blockDeg = (degS != 0);

    float* wchunk = Wg + (size_t)b * S_LEN * S_LEN + (size_t)q0 * S_LEN;
    float* pvb = ws + PV_OFF + ((size_t)(b * 64 + qt) * NC2 + kc) * 4096;

    if (kstart > qt && !blockDeg) {
        // entire chunk strictly future, no degenerate rows: zeros everywhere
        const float4 z = {0.f, 0.f, 0.f, 0.f};
        for (int kt = kstart; kt < kstart + 8; ++kt) {
            float* wbase = wchunk + kt * 64;
            #pragma unroll
            for (int i = 0; i < 4; ++i) {
                int f4 = i * 256 + tid;
                int r  = f4 >> 4;
                int c4 = (f4 & 15) * 4;
                *(float4*)(wbase + (size_t)r * S_LEN + c4) = z;
            }
        }
        #pragma unroll
        for (int i = 0; i < 4; ++i) *(float4*)(pvb + (size_t)(i * 256 + tid) * 4) = z;
        return;
    }

    // Q fragments direct from global (L2-resident: same Q read by all 8 kc-chunks)
    bf16x8 qa[2];
    {
        const float* qrow = Qg + ((size_t)b * S_LEN + q0 + 16 * w + c) * D_DIM;
        #pragma unroll
        for (int ks = 0; ks < 2; ++ks) {
            float4 a0 = *(const float4*)(qrow + ks * 32 + 8 * g);
            float4 a1 = *(const float4*)(qrow + ks * 32 + 8 * g + 4);
            qa[ks][0]=(bf16_t)a0.x; qa[ks][1]=(bf16_t)a0.y; qa[ks][2]=(bf16_t)a0.z; qa[ks][3]=(bf16_t)a0.w;
            qa[ks][4]=(bf16_t)a1.x; qa[ks][5]=(bf16_t)a1.y; qa[ks][6]=(bf16_t)a1.z; qa[ks][7]=(bf16_t)a1.w;
        }
    }

    float m[4], linv[4];
    #pragma unroll
    for (int r = 0; r < 4; ++r) {
        m[r]    = Mrow[16 * w + 4 * g + r];
        linv[r] = Lrow[16 * w + 4 * g + r];
    }
    const int qgBase = q0 + 16 * w + 4 * g;

    f32x4v o[4];
    #pragma unroll
    for (int dt = 0; dt < 4; ++dt) o[dt] = (f32x4v){0.f, 0.f, 0.f, 0.f};

    for (int kt = kstart; kt < kstart + 8; ++kt) {
        const int k0 = kt * 64;
        float* wbase = wchunk + k0;
        const bool cur = (kt <= qt) || blockDeg;

        if (cur) {
            // stage K (bf16x4 vector writes) + V transposed (u16, ~4-way @stride 70)
            const float* ksrc = Kg + ((size_t)b * S_LEN + k0) * D_DIM;
            const float* vsrc = Vg + ((size_t)b * S_LEN + k0) * D_DIM;
            #pragma unroll
            for (int i = 0; i < 4; ++i) {
                int f4 = i * 256 + tid;
                int r  = f4 >> 4;
                int c4 = (f4 & 15) * 4;
                float4 kv = *(const float4*)(ksrc + (size_t)f4 * 4);
                bf16x4v bv;
                bv[0]=(bf16_t)kv.x; bv[1]=(bf16_t)kv.y; bv[2]=(bf16_t)kv.z; bv[3]=(bf16_t)kv.w;
                *(bf16x4v*)&Ks[r][c4] = bv;
                float4 vv = *(const float4*)(vsrc + (size_t)f4 * 4);
                VT[c4 + 0][r] = (bf16_t)vv.x;
                VT[c4 + 1][r] = (bf16_t)vv.y;
                VT[c4 + 2][r] = (bf16_t)vv.z;
                VT[c4 + 3][r] = (bf16_t)vv.w;
            }
            if (tid < 64) pads[tid] = Pg[(size_t)b * S_LEN + k0 + tid] * (-NEG_BIG);
            __syncthreads();

            f32x4v sc[4];
            #pragma unroll
            for (int ct = 0; ct < 4; ++ct) {
                sc[ct] = (f32x4v){0.f, 0.f, 0.f, 0.f};
                #pragma unroll
                for (int ks = 0; ks < 2; ++ks) {
                    bf16x8 kb = *(const bf16x8*)&Ks[ct * 16 + c][ks * 32 + 8 * g];
                    sc[ct] = __builtin_amdgcn_mfma_f32_16x16x32_bf16(qa[ks], kb, sc[ct], 0, 0, 0);
                }
            }
            // weights: global store direct from regs (4x64B segments/instr) + bf16 copy for PV
            #pragma unroll
            for (int ct = 0; ct < 4; ++ct) {
                float pn  = pads[ct * 16 + c];
                int   kgi = k0 + ct * 16 + c;
                #pragma unroll
                for (int r = 0; r < 4; ++r) {
                    float lg = sc[ct][r] * 0.125f + pn;
                    if (kgi > qgBase + r) lg -= NEG_BIG;
                    float wv = __expf(lg - m[r]) * linv[r];   // == exact ref weight
                    wbase[(size_t)(16 * w + 4 * g + r) * S_LEN + ct * 16 + c] = wv;
                    Pf[16 * w + 4 * g + r][ct * 16 + c] = (bf16_t)wv;
                }
            }
            __syncthreads();

            // PV: A = Pf rows (bf16x8), B = V^T tile (conflict-free 4B chunks)
            #pragma unroll
            for (int ks = 0; ks < 2; ++ks) {
                bf16x8 wa = *(const bf16x8*)&Pf[16 * w + c][ks * 32 + 8 * g];
                #pragma unroll
                for (int dt = 0; dt < 4; ++dt) {
                    bf16x8 vb;
                    #pragma unroll
                    for (int p = 0; p < 4; ++p)
                        ((bf16x2v*)&vb)[p] = *(const bf16x2v*)&VT[dt * 16 + c][ks * 32 + 8 * g + 2 * p];
                    o[dt] = __builtin_amdgcn_mfma_f32_16x16x32_bf16(wa, vb, o[dt], 0, 0, 0);
                }
            }
            __syncthreads();
        } else {
            // strictly-future tile, no degenerate rows: weights exactly 0
            const float4 z = {0.f, 0.f, 0.f, 0.f};
            #pragma unroll
            for (int i = 0; i < 4; ++i) {
                int f4 = i * 256 + tid;
                int r  = f4 >> 4;
                int c4 = (f4 & 15) * 4;
                *(float4*)(wbase + (size_t)r * S_LEN + c4) = z;
            }
        }
    }

    #pragma unroll
    for (int dt = 0; dt < 4; ++dt)
        #pragma unroll
        for (int r = 0; r < 4; ++r)
            pvb[(size_t)(16 * w + 4 * g + r) * 64 + dt * 16 + c] = o[dt][r];
}

// ---------------- kernel 3: reduce PV partials -> context ----------------
__global__ void pv_reduce(const float* __restrict__ ws, float* __restrict__ Og)
{
    const size_t i = (size_t)blockIdx.x * 256 + threadIdx.x;   // 0 .. 2M-1
    const size_t bq = i >> 12;                                  // b*64 + qt
    const size_t lo = i & 4095;                                 // row*64 + d
    const float* p = ws + PV_OFF + bq * NC2 * 4096 + lo;
    float s = 0.f;
    #pragma unroll
    for (int kc2 = 0; kc2 < NC2; ++kc2) s += p[(size_t)kc2 * 4096];
    Og[i] = s;
}

// ---------------- fallback: monolithic kernel (used only if ws too small) ----------------
__global__ __launch_bounds__(256, 2)
void sdpa_fused(const float* __restrict__ Qg,
                const float* __restrict__ Kg,
                const float* __restrict__ Vg,
                const float* __restrict__ Pg,
                float* __restrict__ Og,
                float* __restrict__ Wg)
{
    __shared__ __align__(16) bf16_t Qs[64][72];
    __shared__ __align__(16) bf16_t Ks[64][72];
    __shared__ __align__(16) bf16_t VT[64][72];
    __shared__ __align__(16) float  Wf[64][68];
    __shared__ float pads[64];
    __shared__ float red[4];
    __shared__ int   anyDeg;

    const int tid  = threadIdx.x;
    const int w    = tid >> 6;
    const int lane = tid & 63;
    const int g    = lane >> 4;
    const int c    = lane & 15;
    const int b    = blockIdx.x & 7;
    const int qt   = 63 - (blockIdx.x >> 3);
    const int q0   = qt * 64;

    if (tid == 0) anyDeg = 0;

    {
        const float* src = Qg + ((size_t)b * S_LEN + q0) * D_DIM;
        #pragma unroll
        for (int i = 0; i < 4; ++i) {
            int f4 = i * 256 + tid;
            int r  = f4 >> 4;
            int c4 = (f4 & 15) * 4;
            float4 v4 = *(const float4*)(src + (size_t)f4 * 4);
            bf16x4v bv;
            bv[0]=(bf16_t)v4.x; bv[1]=(bf16_t)v4.y; bv[2]=(bf16_t)v4.z; bv[3]=(bf16_t)v4.w;
            *(bf16x4v*)&Qs[r][c4] = bv;
        }
    }
    __syncthreads();

    bf16x8 qa[2];
    {
        int row = 16 * w + c;
        #pragma unroll
        for (int ks = 0; ks < 2; ++ks)
            qa[ks] = *(const bf16x8*)&Qs[row][ks * 32 + 8 * g];
    }

    float m[4], l[4];
    #pragma unroll
    for (int r = 0; r < 4; ++r) { m[r] = -INFINITY; l[r] = 0.f; }
    const int qgBase = q0 + 16 * w + 4 * g;

    for (int kt = 0; kt <= qt; ++kt) {
        const int k0 = kt * 64;
        {
            const float* src = Kg + ((size_t)b * S_LEN + k0) * D_DIM;
            #pragma unroll
            for (int i = 0; i < 4; ++i) {
                int f4 = i * 256 + tid;
                int r  = f4 >> 4;
                int c4 = (f4 & 15) * 4;
                float4 v4 = *(const float4*)(src + (size_t)f4 * 4);
                bf16x4v bv;
                bv[0]=(bf16_t)v4.x; bv[1]=(bf16_t)v4.y; bv[2]=(bf16_t)v4.z; bv[3]=(bf16_t)v4.w;
                *(bf16x4v*)&Ks[r][c4] = bv;
            }
            if (tid < 64) pads[tid] = Pg[(size_t)b * S_LEN + k0 + tid] * (-NEG_BIG);
        }
        __syncthreads();

        f32x4v sc[4];
        #pragma unroll
        for (int ct = 0; ct < 4; ++ct) {
            sc[ct] = (f32x4v){0.f, 0.f, 0.f, 0.f};
            #pragma unroll
            for (int ks = 0; ks < 2; ++ks) {
                bf16x8 kb = *(const bf16x8*)&Ks[ct * 16 + c][ks * 32 + 8 * g];
                sc[ct] = __builtin_amdgcn_mfma_f32_16x16x32_bf16(qa[ks], kb, sc[ct], 0, 0, 0);
            }
        }
        float l4[4][4];
        #pragma unroll
        for (int ct = 0; ct < 4; ++ct) {
            float pn  = pads[ct * 16 + c];
            int   kgi = k0 + ct * 16 + c;
            #pragma unroll
            for (int r = 0; r < 4; ++r) {
                float lg = sc[ct][r] * 0.125f + pn;
                if (kgi > qgBase + r) lg -= NEG_BIG;
                l4[ct][r] = lg;
            }
        }
        #pragma unroll
        for (int r = 0; r < 4; ++r) {
            float tm = fmaxf(fmaxf(l4[0][r], l4[1][r]), fmaxf(l4[2][r], l4[3][r]));
            tm = fmaxf(tm, __shfl_xor(tm, 1));
            tm = fmaxf(tm, __shfl_xor(tm, 2));
            tm = fmaxf(tm, __shfl_xor(tm, 4));
            tm = fmaxf(tm, __shfl_xor(tm, 8));
            float mnew = fmaxf(m[r], tm);
            float s = __expf(l4[0][r] - mnew) + __expf(l4[1][r] - mnew)
                    + __expf(l4[2][r] - mnew) + __expf(l4[3][r] - mnew);
            s += __shfl_xor(s, 1);
            s += __shfl_xor(s, 2);
            s += __shfl_xor(s, 4);
            s += __shfl_xor(s, 8);
            l[r] = l[r] * __expf(m[r] - mnew) + s;
            m[r] = mnew;
        }
        __syncthreads();
    }

    {
        float cnt = 0.f;
        const float* pb = Pg + (size_t)b * S_LEN;
        for (int i = tid; i < S_LEN; i += 256) cnt += 1.f - pb[i];
        #pragma unroll
        for (int off = 32; off >= 1; off >>= 1) cnt += __shfl_down(cnt, off);
        if (lane == 0) red[w] = cnt;
    }
    __syncthreads();
    {
        float nonpad = red[0] + red[1] + red[2] + red[3];
        bool deg = false;
        #pragma unroll
        for (int r = 0; r < 4; ++r)
            if (m[r] < -1.0e14f) { l[r] += nonpad; deg = true; }
        if (deg) anyDeg = 1;
    }
    __syncthreads();
    const bool blockDeg = (anyDeg != 0);
    float linv[4];
    #pragma unroll
    for (int r = 0; r < 4; ++r) linv[r] = 1.f / l[r];

    f32x4v o[4];
    #pragma unroll
    for (int dt = 0; dt < 4; ++dt) o[dt] = (f32x4v){0.f, 0.f, 0.f, 0.f};

    for (int kt = 0; kt < 64; ++kt) {
        const int k0 = kt * 64;
        float* wbase = Wg + (size_t)b * S_LEN * S_LEN + (size_t)q0 * S_LEN + k0;

        if (kt <= qt || blockDeg) {
            const float* ksrc = Kg + ((size_t)b * S_LEN + k0) * D_DIM;
            const float* vsrc = Vg + ((size_t)b * S_LEN + k0) * D_DIM;
            #pragma unroll
            for (int i = 0; i < 4; ++i) {
                int f4 = i * 256 + tid;
                int r  = f4 >> 4;
                int c4 = (f4 & 15) * 4;
                float4 kv = *(const float4*)(ksrc + (size_t)f4 * 4);
                bf16x4v bv;
                bv[0]=(bf16_t)kv.x; bv[1]=(bf16_t)kv.y; bv[2]=(bf16_t)kv.z; bv[3]=(bf16_t)kv.w;
                *(bf16x4v*)&Ks[r][c4] = bv;
                float4 vv = *(const float4*)(vsrc + (size_t)f4 * 4);
                VT[c4 + 0][r] = (bf16_t)vv.x;
                VT[c4 + 1][r] = (bf16_t)vv.y;
                VT[c4 + 2][r] = (bf16_t)vv.z;
                VT[c4 + 3][r] = (bf16_t)vv.w;
            }
            if (tid < 64) pads[tid] = Pg[(size_t)b * S_LEN + k0 + tid] * (-NEG_BIG);
            __syncthreads();

            f32x4v sc[4];
            #pragma unroll
            for (int ct = 0; ct < 4; ++ct) {
                sc[ct] = (f32x4v){0.f, 0.f, 0.f, 0.f};
                #pragma unroll
                for (int ks = 0; ks < 2; ++ks) {
                    bf16x8 kb = *(const bf16x8*)&Ks[ct * 16 + c][ks * 32 + 8 * g];
                    sc[ct] = __builtin_amdgcn_mfma_f32_16x16x32_bf16(qa[ks], kb, sc[ct], 0, 0, 0);
                }
            }
            #pragma unroll
            for (int ct = 0; ct < 4; ++ct) {
                float pn  = pads[ct * 16 + c];
                int   kgi = k0 + ct * 16 + c;
                #pragma unroll
                for (int r = 0; r < 4; ++r) {
                    float lg = sc[ct][r] * 0.125f + pn;
                    if (kgi > qgBase + r) lg -= NEG_BIG;
                    float wv = __expf(lg - m[r]) * linv[r];
                    Wf[16 * w + 4 * g + r][ct * 16 + c] = wv;
                }
            }
            __syncthreads();

            #pragma unroll
            for (int i = 0; i < 4; ++i) {
                int f4 = i * 256 + tid;
                int r  = f4 >> 4;
                int c4 = (f4 & 15) * 4;
                float4 wv = *(const float4*)&Wf[r][c4];
                *(float4*)(wbase + (size_t)r * S_LEN + c4) = wv;
            }

            #pragma unroll
            for (int ks = 0; ks < 2; ++ks) {
                float4 f0 = *(const float4*)&Wf[16 * w + c][ks * 32 + 8 * g];
                float4 f1 = *(const float4*)&Wf[16 * w + c][ks * 32 + 8 * g + 4];
                bf16x8 wa;
                wa[0]=(bf16_t)f0.x; wa[1]=(bf16_t)f0.y; wa[2]=(bf16_t)f0.z; wa[3]=(bf16_t)f0.w;
                wa[4]=(bf16_t)f1.x; wa[5]=(bf16_t)f1.y; wa[6]=(bf16_t)f1.z; wa[7]=(bf16_t)f1.w;
                #pragma unroll
                for (int dt = 0; dt < 4; ++dt) {
                    bf16x8 vb = *(const bf16x8*)&VT[dt * 16 + c][ks * 32 + 8 * g];
                    o[dt] = __builtin_amdgcn_mfma_f32_16x16x32_bf16(wa, vb, o[dt], 0, 0, 0);
                }
            }
            __syncthreads();
        } else {
            const float4 z = {0.f, 0.f, 0.f, 0.f};
            #pragma unroll
            for (int i = 0; i < 4; ++i) {
                int f4 = i * 256 + tid;
                int r  = f4 >> 4;
                int c4 = (f4 & 15) * 4;
                *(float4*)(wbase + (size_t)r * S_LEN + c4) = z;
            }
        }
    }

    #pragma unroll
    for (int dt = 0; dt < 4; ++dt)
        #pragma unroll
        for (int r = 0; r < 4; ++r)
            Og[((size_t)b * S_LEN + (q0 + 16 * w + 4 * g + r)) * D_DIM + dt * 16 + c] = o[dt][r];
}

extern "C" void kernel_launch(void* const* d_in, const int* in_sizes, int n_in,
                              void* d_out, int out_size, void* d_ws, size_t ws_size,
                              hipStream_t stream) {
    const float* q   = (const float*)d_in[0];
    const float* k   = (const float*)d_in[1];
    const float* v   = (const float*)d_in[2];
    const float* pad = (const float*)d_in[3];

    float* out  = (float*)d_out;
    float* ctx  = out;
    float* attw = out + (size_t)8 * 4096 * 64;
    float* ws   = (float*)d_ws;

    if (ws_size >= (size_t)WS_FLOATS_NEEDED * 4) {
        hipLaunchKernelGGL(npad_count, dim3(8), dim3(256), 0, stream, pad, ws);
        hipLaunchKernelGGL(sdpa_stats, dim3(8 * 64 * NC1), dim3(256), 0, stream, q, k, pad, ws);
        hipLaunchKernelGGL(sdpa_wpv,   dim3(8 * 64 * NC2), dim3(256), 0, stream, q, k, v, pad, attw, ws);
        hipLaunchKernelGGL(pv_reduce,  dim3(8 * 4096 * 64 / 256), dim3(256), 0, stream, ws, ctx);
    } else {
        hipLaunchKernelGGL(sdpa_fused, dim3(512), dim3(256), 0, stream, q, k, v, pad, ctx, attw);
    }
}

// Round 6
// 192.615 us; speedup vs baseline: 1.4513x; 1.3266x over previous
//
#include <hip/hip_runtime.h>

#define S_LEN 4096
#define D_DIM 64
#define NEG_BIG 1.0e15f
#define NC1 8          // k-chunks (8 tiles each)
#define SSTAT (8 * 64 * NC1 * 64)           // floats: [b][qt][kc][64] row partial sums
#define NPAD_OFF SSTAT                      // [0..7]=npadTot, [8..15]=firstNonPad
#define WS_FLOATS_NEEDED (NPAD_OFF + 16)
#define VSTRIDE 70     // odd word-stride: transpose u16 writes ~conflict-free

typedef __bf16 bf16_t;
typedef bf16_t bf16x8 __attribute__((ext_vector_type(8)));
typedef bf16_t bf16x4v __attribute__((ext_vector_type(4)));
typedef bf16_t bf16x2v __attribute__((ext_vector_type(2)));
typedef float f32x4v __attribute__((ext_vector_type(4)));

// ---------------- kernel 1: partial softmax DENOMINATORS (no max needed) ----
// Also: blocks gx>=2048 zero a ctx slice; block t==511 computes npad stats.
__global__ __launch_bounds__(256, 2)
void sdpa_stats(const float* __restrict__ Qg,
                const float* __restrict__ Kg,
                const float* __restrict__ Pg,
                float* __restrict__ ws,
                float* __restrict__ ctx)
{
    __shared__ __align__(16) bf16_t Ks[64][72];
    __shared__ float pads[64];

    const int tid  = threadIdx.x;
    const int w    = tid >> 6;
    const int lane = tid & 63;
    const int g    = lane >> 4;
    const int c    = lane & 15;
    const int gx   = blockIdx.x;
    const int b    = gx & 7;            // batch -> XCD pinning
    const int t    = gx >> 3;
    const int qt   = 63 - (t & 63);     // qt descending within each kc
    const int kc   = t >> 6;
    const int q0   = qt * 64;

    // ctx zeroing spread over the later-launched half of the grid
    if (gx >= 2048) {
        f32x4v z = {0.f, 0.f, 0.f, 0.f};
        *(f32x4v*)(ctx + (size_t)(gx - 2048) * 1024 + tid * 4) = z;
    }

    const size_t soff = ((size_t)((b * 64 + qt) * NC1 + kc)) * 64;

    if (kc * 8 > qt) {                  // chunk entirely future: sum contribution 0
        if (tid < 64) ws[soff + tid] = 0.f;
        if (t == 511) {                 // npad duty: one light block per batch
            float cnt = 0.f, first = (float)S_LEN;
            const float* pb = Pg + (size_t)b * S_LEN;
            for (int i = tid; i < S_LEN; i += 256) {
                float p = pb[i];
                cnt += 1.f - p;
                if (p == 0.f) first = fminf(first, (float)i);
            }
            #pragma unroll
            for (int off = 32; off >= 1; off >>= 1) {
                cnt += __shfl_down(cnt, off);
                first = fminf(first, __shfl_down(first, off));
            }
            if (lane == 0) { pads[w] = cnt; pads[8 + w] = first; }
            __syncthreads();
            if (tid == 0) {
                ws[NPAD_OFF + b]     = pads[0] + pads[1] + pads[2] + pads[3];
                ws[NPAD_OFF + 8 + b] = fminf(fminf(pads[8], pads[9]), fminf(pads[10], pads[11]));
            }
        }
        return;
    }

    // Q fragments direct from global (row 16w+c, d = 8g+j+32ks)
    bf16x8 qa[2];
    {
        const float* qrow = Qg + ((size_t)b * S_LEN + q0 + 16 * w + c) * D_DIM;
        #pragma unroll
        for (int ks = 0; ks < 2; ++ks) {
            float4 a0 = *(const float4*)(qrow + ks * 32 + 8 * g);
            float4 a1 = *(const float4*)(qrow + ks * 32 + 8 * g + 4);
            qa[ks][0]=(bf16_t)a0.x; qa[ks][1]=(bf16_t)a0.y; qa[ks][2]=(bf16_t)a0.z; qa[ks][3]=(bf16_t)a0.w;
            qa[ks][4]=(bf16_t)a1.x; qa[ks][5]=(bf16_t)a1.y; qa[ks][6]=(bf16_t)a1.z; qa[ks][7]=(bf16_t)a1.w;
        }
    }

    float l[4] = {0.f, 0.f, 0.f, 0.f};
    const int qgBase = q0 + 16 * w + 4 * g;
    const int kend = min(kc * 8 + 8, qt + 1);

    for (int kt = kc * 8; kt < kend; ++kt) {
        const int k0 = kt * 64;
        {
            const float* src = Kg + ((size_t)b * S_LEN + k0) * D_DIM;
            #pragma unroll
            for (int i = 0; i < 4; ++i) {
                int f4 = i * 256 + tid;
                int r  = f4 >> 4;
                int c4 = (f4 & 15) * 4;
                float4 v4 = *(const float4*)(src + (size_t)f4 * 4);
                bf16x4v bv;
                bv[0]=(bf16_t)v4.x; bv[1]=(bf16_t)v4.y; bv[2]=(bf16_t)v4.z; bv[3]=(bf16_t)v4.w;
                *(bf16x4v*)&Ks[r][c4] = bv;
            }
            if (tid < 64) pads[tid] = Pg[(size_t)b * S_LEN + k0 + tid] * (-NEG_BIG);
        }
        __syncthreads();

        f32x4v sc[4];
        #pragma unroll
        for (int ct = 0; ct < 4; ++ct) {
            sc[ct] = (f32x4v){0.f, 0.f, 0.f, 0.f};
            #pragma unroll
            for (int ks = 0; ks < 2; ++ks) {
                bf16x8 kb = *(const bf16x8*)&Ks[ct * 16 + c][ks * 32 + 8 * g];
                sc[ct] = __builtin_amdgcn_mfma_f32_16x16x32_bf16(qa[ks], kb, sc[ct], 0, 0, 0);
            }
        }
        // no max tracking: exp(-1e15)=0 handles masks; logits are O(5)
        float rs[4] = {0.f, 0.f, 0.f, 0.f};
        #pragma unroll
        for (int ct = 0; ct < 4; ++ct) {
            float pn  = pads[ct * 16 + c];
            int   kgi = k0 + ct * 16 + c;
            #pragma unroll
            for (int r = 0; r < 4; ++r) {
                float lg = sc[ct][r] * 0.125f + pn;
                if (kgi > qgBase + r) lg -= NEG_BIG;
                rs[r] += __expf(lg);
            }
        }
        #pragma unroll
        for (int r = 0; r < 4; ++r) {
            float s = rs[r];
            s += __shfl_xor(s, 1);
            s += __shfl_xor(s, 2);
            s += __shfl_xor(s, 4);
            s += __shfl_xor(s, 8);
            l[r] += s;
        }
        __syncthreads();
    }

    if (c == 0) {
        #pragma unroll
        for (int r = 0; r < 4; ++r)
            ws[soff + 16 * w + 4 * g + r] = l[r];
    }
}

// ---------------- kernel 2: W tiles (nt stores) + PV atomically into ctx ----
__global__ __launch_bounds__(256, 2)
void sdpa_wpv(const float* __restrict__ Qg,
              const float* __restrict__ Kg,
              const float* __restrict__ Vg,
              const float* __restrict__ Pg,
              float* __restrict__ Wg,
              float* __restrict__ ws,
              float* __restrict__ ctx)
{
    __shared__ __align__(16) bf16_t Ks[64][72];
    __shared__ __align__(16) bf16_t VT[64][VSTRIDE];   // VT[d][k_local]
    __shared__ __align__(16) bf16_t Pf[64][72];        // bf16 weights for PV A-frags
    __shared__ float pads[64];
    __shared__ float Lrow[64];

    const int tid  = threadIdx.x;
    const int w    = tid >> 6;
    const int lane = tid & 63;
    const int g    = lane >> 4;
    const int c    = lane & 15;
    const int gx   = blockIdx.x;
    const int b    = gx & 7;
    const int t    = gx >> 3;
    const int qt   = 63 - (t & 63);
    const int kc   = t >> 6;
    const int q0   = qt * 64;
    const int kstart = kc * 8;

    const float npadTot = ws[NPAD_OFF + b];
    const float firstNP = ws[NPAD_OFF + 8 + b];
    const bool  blockDeg = ((float)q0 < firstNP);   // tile contains degenerate rows

    // combine partial denominators: L = sum of 8 chunk sums (deg rows: count formula)
    if (tid < 64) {
        int qrow = q0 + tid;
        float L;
        if ((float)qrow < firstNP) {
            L = (float)(qrow + 1) + npadTot;        // #causal(all padded) + #future nonpad
        } else {
            const float* sb = ws + (size_t)(b * 64 + qt) * NC1 * 64 + tid;
            L = 0.f;
            #pragma unroll
            for (int i = 0; i < NC1; ++i) L += sb[(size_t)i * 64];
        }
        Lrow[tid] = 1.f / L;
    }
    __syncthreads();

    float* wchunk = Wg + (size_t)b * S_LEN * S_LEN + (size_t)q0 * S_LEN;

    if (kstart > qt && !blockDeg) {
        // entire chunk strictly future, no degenerate rows: zeros (nt streaming)
        const f32x4v z = {0.f, 0.f, 0.f, 0.f};
        for (int kt = kstart; kt < kstart + 8; ++kt) {
            float* wbase = wchunk + kt * 64;
            #pragma unroll
            for (int i = 0; i < 4; ++i) {
                int f4 = i * 256 + tid;
                int r  = f4 >> 4;
                int c4 = (f4 & 15) * 4;
                __builtin_nontemporal_store(z, (f32x4v*)(wbase + (size_t)r * S_LEN + c4));
            }
        }
        return;
    }

    // Q fragments direct from global (L2-resident across kc-chunks)
    bf16x8 qa[2];
    {
        const float* qrow = Qg + ((size_t)b * S_LEN + q0 + 16 * w + c) * D_DIM;
        #pragma unroll
        for (int ks = 0; ks < 2; ++ks) {
            float4 a0 = *(const float4*)(qrow + ks * 32 + 8 * g);
            float4 a1 = *(const float4*)(qrow + ks * 32 + 8 * g + 4);
            qa[ks][0]=(bf16_t)a0.x; qa[ks][1]=(bf16_t)a0.y; qa[ks][2]=(bf16_t)a0.z; qa[ks][3]=(bf16_t)a0.w;
            qa[ks][4]=(bf16_t)a1.x; qa[ks][5]=(bf16_t)a1.y; qa[ks][6]=(bf16_t)a1.z; qa[ks][7]=(bf16_t)a1.w;
        }
    }

    const int qgBase = q0 + 16 * w + 4 * g;
    float linv[4];
    #pragma unroll
    for (int r = 0; r < 4; ++r) linv[r] = Lrow[16 * w + 4 * g + r];

    f32x4v o[4];
    #pragma unroll
    for (int dt = 0; dt < 4; ++dt) o[dt] = (f32x4v){0.f, 0.f, 0.f, 0.f};

    for (int kt = kstart; kt < kstart + 8; ++kt) {
        const int k0 = kt * 64;
        float* wbase = wchunk + k0;
        const bool cur = (kt <= qt) || blockDeg;

        if (cur) {
            const float* ksrc = Kg + ((size_t)b * S_LEN + k0) * D_DIM;
            const float* vsrc = Vg + ((size_t)b * S_LEN + k0) * D_DIM;
            #pragma unroll
            for (int i = 0; i < 4; ++i) {
                int f4 = i * 256 + tid;
                int r  = f4 >> 4;
                int c4 = (f4 & 15) * 4;
                float4 kv = *(const float4*)(ksrc + (size_t)f4 * 4);
                bf16x4v bv;
                bv[0]=(bf16_t)kv.x; bv[1]=(bf16_t)kv.y; bv[2]=(bf16_t)kv.z; bv[3]=(bf16_t)kv.w;
                *(bf16x4v*)&Ks[r][c4] = bv;
                float4 vv = *(const float4*)(vsrc + (size_t)f4 * 4);
                VT[c4 + 0][r] = (bf16_t)vv.x;
                VT[c4 + 1][r] = (bf16_t)vv.y;
                VT[c4 + 2][r] = (bf16_t)vv.z;
                VT[c4 + 3][r] = (bf16_t)vv.w;
            }
            if (tid < 64) pads[tid] = Pg[(size_t)b * S_LEN + k0 + tid] * (-NEG_BIG);
            __syncthreads();

            f32x4v sc[4];
            #pragma unroll
            for (int ct = 0; ct < 4; ++ct) {
                sc[ct] = (f32x4v){0.f, 0.f, 0.f, 0.f};
                #pragma unroll
                for (int ks = 0; ks < 2; ++ks) {
                    bf16x8 kb = *(const bf16x8*)&Ks[ct * 16 + c][ks * 32 + 8 * g];
                    sc[ct] = __builtin_amdgcn_mfma_f32_16x16x32_bf16(qa[ks], kb, sc[ct], 0, 0, 0);
                }
            }
            if (!blockDeg) {
                #pragma unroll
                for (int ct = 0; ct < 4; ++ct) {
                    float pn  = pads[ct * 16 + c];
                    int   kgi = k0 + ct * 16 + c;
                    #pragma unroll
                    for (int r = 0; r < 4; ++r) {
                        float lg = sc[ct][r] * 0.125f + pn;
                        if (kgi > qgBase + r) lg -= NEG_BIG;
                        float wv = __expf(lg) * linv[r];        // == ref weight (no-max form)
                        __builtin_nontemporal_store(wv,
                            wbase + (size_t)(16 * w + 4 * g + r) * S_LEN + ct * 16 + c);
                        Pf[16 * w + 4 * g + r][ct * 16 + c] = (bf16_t)wv;
                    }
                }
            } else {
                #pragma unroll
                for (int ct = 0; ct < 4; ++ct) {
                    float pn  = pads[ct * 16 + c];
                    int   kgi = k0 + ct * 16 + c;
                    #pragma unroll
                    for (int r = 0; r < 4; ++r) {
                        float lg = sc[ct][r] * 0.125f + pn;
                        if (kgi > qgBase + r) lg -= NEG_BIG;
                        float wv = __expf(lg) * linv[r];
                        if ((float)(qgBase + r) < firstNP)      // degenerate row: indicator/L
                            wv = (kgi <= qgBase + r || pn == 0.f) ? linv[r] : 0.f;
                        __builtin_nontemporal_store(wv,
                            wbase + (size_t)(16 * w + 4 * g + r) * S_LEN + ct * 16 + c);
                        Pf[16 * w + 4 * g + r][ct * 16 + c] = (bf16_t)wv;
                    }
                }
            }
            __syncthreads();

            // PV: A = Pf rows (bf16x8), B = V^T tile
            #pragma unroll
            for (int ks = 0; ks < 2; ++ks) {
                bf16x8 wa = *(const bf16x8*)&Pf[16 * w + c][ks * 32 + 8 * g];
                #pragma unroll
                for (int dt = 0; dt < 4; ++dt) {
                    bf16x8 vb;
                    #pragma unroll
                    for (int p = 0; p < 4; ++p)
                        ((bf16x2v*)&vb)[p] = *(const bf16x2v*)&VT[dt * 16 + c][ks * 32 + 8 * g + 2 * p];
                    o[dt] = __builtin_amdgcn_mfma_f32_16x16x32_bf16(wa, vb, o[dt], 0, 0, 0);
                }
            }
            __syncthreads();
        } else {
            const f32x4v z = {0.f, 0.f, 0.f, 0.f};
            #pragma unroll
            for (int i = 0; i < 4; ++i) {
                int f4 = i * 256 + tid;
                int r  = f4 >> 4;
                int c4 = (f4 & 15) * 4;
                __builtin_nontemporal_store(z, (f32x4v*)(wbase + (size_t)r * S_LEN + c4));
            }
        }
    }

    // accumulate partial PV straight into ctx (zeroed by sdpa_stats)
    #pragma unroll
    for (int dt = 0; dt < 4; ++dt)
        #pragma unroll
        for (int r = 0; r < 4; ++r)
            atomicAdd(&ctx[((size_t)b * S_LEN + (q0 + 16 * w + 4 * g + r)) * D_DIM + dt * 16 + c],
                      o[dt][r]);
}

// ---------------- fallback: monolithic kernel (used only if ws too small) ----
__global__ __launch_bounds__(256, 2)
void sdpa_fused(const float* __restrict__ Qg,
                const float* __restrict__ Kg,
                const float* __restrict__ Vg,
                const float* __restrict__ Pg,
                float* __restrict__ Og,
                float* __restrict__ Wg)
{
    __shared__ __align__(16) bf16_t Qs[64][72];
    __shared__ __align__(16) bf16_t Ks[64][72];
    __shared__ __align__(16) bf16_t VT[64][72];
    __shared__ __align__(16) float  Wf[64][68];
    __shared__ float pads[64];
    __shared__ float red[4];
    __shared__ int   anyDeg;

    const int tid  = threadIdx.x;
    const int w    = tid >> 6;
    const int lane = tid & 63;
    const int g    = lane >> 4;
    const int c    = lane & 15;
    const int b    = blockIdx.x & 7;
    const int qt   = 63 - (blockIdx.x >> 3);
    const int q0   = qt * 64;

    if (tid == 0) anyDeg = 0;

    {
        const float* src = Qg + ((size_t)b * S_LEN + q0) * D_DIM;
        #pragma unroll
        for (int i = 0; i < 4; ++i) {
            int f4 = i * 256 + tid;
            int r  = f4 >> 4;
            int c4 = (f4 & 15) * 4;
            float4 v4 = *(const float4*)(src + (size_t)f4 * 4);
            bf16x4v bv;
            bv[0]=(bf16_t)v4.x; bv[1]=(bf16_t)v4.y; bv[2]=(bf16_t)v4.z; bv[3]=(bf16_t)v4.w;
            *(bf16x4v*)&Qs[r][c4] = bv;
        }
    }
    __syncthreads();

    bf16x8 qa[2];
    {
        int row = 16 * w + c;
        #pragma unroll
        for (int ks = 0; ks < 2; ++ks)
            qa[ks] = *(const bf16x8*)&Qs[row][ks * 32 + 8 * g];
    }

    float m[4], l[4];
    #pragma unroll
    for (int r = 0; r < 4; ++r) { m[r] = -INFINITY; l[r] = 0.f; }
    const int qgBase = q0 + 16 * w + 4 * g;

    for (int kt = 0; kt <= qt; ++kt) {
        const int k0 = kt * 64;
        {
            const float* src = Kg + ((size_t)b * S_LEN + k0) * D_DIM;
            #pragma unroll
            for (int i = 0; i < 4; ++i) {
                int f4 = i * 256 + tid;
                int r  = f4 >> 4;
                int c4 = (f4 & 15) * 4;
                float4 v4 = *(const float4*)(src + (size_t)f4 * 4);
                bf16x4v bv;
                bv[0]=(bf16_t)v4.x; bv[1]=(bf16_t)v4.y; bv[2]=(bf16_t)v4.z; bv[3]=(bf16_t)v4.w;
                *(bf16x4v*)&Ks[r][c4] = bv;
            }
            if (tid < 64) pads[tid] = Pg[(size_t)b * S_LEN + k0 + tid] * (-NEG_BIG);
        }
        __syncthreads();

        f32x4v sc[4];
        #pragma unroll
        for (int ct = 0; ct < 4; ++ct) {
            sc[ct] = (f32x4v){0.f, 0.f, 0.f, 0.f};
            #pragma unroll
            for (int ks = 0; ks < 2; ++ks) {
                bf16x8 kb = *(const bf16x8*)&Ks[ct * 16 + c][ks * 32 + 8 * g];
                sc[ct] = __builtin_amdgcn_mfma_f32_16x16x32_bf16(qa[ks], kb, sc[ct], 0, 0, 0);
            }
        }
        float l4[4][4];
        #pragma unroll
        for (int ct = 0; ct < 4; ++ct) {
            float pn  = pads[ct * 16 + c];
            int   kgi = k0 + ct * 16 + c;
            #pragma unroll
            for (int r = 0; r < 4; ++r) {
                float lg = sc[ct][r] * 0.125f + pn;
                if (kgi > qgBase + r) lg -= NEG_BIG;
                l4[ct][r] = lg;
            }
        }
        #pragma unroll
        for (int r = 0; r < 4; ++r) {
            float tm = fmaxf(fmaxf(l4[0][r], l4[1][r]), fmaxf(l4[2][r], l4[3][r]));
            tm = fmaxf(tm, __shfl_xor(tm, 1));
            tm = fmaxf(tm, __shfl_xor(tm, 2));
            tm = fmaxf(tm, __shfl_xor(tm, 4));
            tm = fmaxf(tm, __shfl_xor(tm, 8));
            float mnew = fmaxf(m[r], tm);
            float s = __expf(l4[0][r] - mnew) + __expf(l4[1][r] - mnew)
                    + __expf(l4[2][r] - mnew) + __expf(l4[3][r] - mnew);
            s += __shfl_xor(s, 1);
            s += __shfl_xor(s, 2);
            s += __shfl_xor(s, 4);
            s += __shfl_xor(s, 8);
            l[r] = l[r] * __expf(m[r] - mnew) + s;
            m[r] = mnew;
        }
        __syncthreads();
    }

    {
        float cnt = 0.f;
        const float* pb = Pg + (size_t)b * S_LEN;
        for (int i = tid; i < S_LEN; i += 256) cnt += 1.f - pb[i];
        #pragma unroll
        for (int off = 32; off >= 1; off >>= 1) cnt += __shfl_down(cnt, off);
        if (lane == 0) red[w] = cnt;
    }
    __syncthreads();
    {
        float nonpad = red[0] + red[1] + red[2] + red[3];
        bool deg = false;
        #pragma unroll
        for (int r = 0; r < 4; ++r)
            if (m[r] < -1.0e14f) { l[r] += nonpad; deg = true; }
        if (deg) anyDeg = 1;
    }
    __syncthreads();
    const bool blockDeg = (anyDeg != 0);
    float linv[4];
    #pragma unroll
    for (int r = 0; r < 4; ++r) linv[r] = 1.f / l[r];

    f32x4v o[4];
    #pragma unroll
    for (int dt = 0; dt < 4; ++dt) o[dt] = (f32x4v){0.f, 0.f, 0.f, 0.f};

    for (int kt = 0; kt < 64; ++kt) {
        const int k0 = kt * 64;
        float* wbase = Wg + (size_t)b * S_LEN * S_LEN + (size_t)q0 * S_LEN + k0;

        if (kt <= qt || blockDeg) {
            const float* ksrc = Kg + ((size_t)b * S_LEN + k0) * D_DIM;
            const float* vsrc = Vg + ((size_t)b * S_LEN + k0) * D_DIM;
            #pragma unroll
            for (int i = 0; i < 4; ++i) {
                int f4 = i * 256 + tid;
                int r  = f4 >> 4;
                int c4 = (f4 & 15) * 4;
                float4 kv = *(const float4*)(ksrc + (size_t)f4 * 4);
                bf16x4v bv;
                bv[0]=(bf16_t)kv.x; bv[1]=(bf16_t)kv.y; bv[2]=(bf16_t)kv.z; bv[3]=(bf16_t)kv.w;
                *(bf16x4v*)&Ks[r][c4] = bv;
                float4 vv = *(const float4*)(vsrc + (size_t)f4 * 4);
                VT[c4 + 0][r] = (bf16_t)vv.x;
                VT[c4 + 1][r] = (bf16_t)vv.y;
                VT[c4 + 2][r] = (bf16_t)vv.z;
                VT[c4 + 3][r] = (bf16_t)vv.w;
            }
            if (tid < 64) pads[tid] = Pg[(size_t)b * S_LEN + k0 + tid] * (-NEG_BIG);
            __syncthreads();

            f32x4v sc[4];
            #pragma unroll
            for (int ct = 0; ct < 4; ++ct) {
                sc[ct] = (f32x4v){0.f, 0.f, 0.f, 0.f};
                #pragma unroll
                for (int ks = 0; ks < 2; ++ks) {
                    bf16x8 kb = *(const bf16x8*)&Ks[ct * 16 + c][ks * 32 + 8 * g];
                    sc[ct] = __builtin_amdgcn_mfma_f32_16x16x32_bf16(qa[ks], kb, sc[ct], 0, 0, 0);
                }
            }
            #pragma unroll
            for (int ct = 0; ct < 4; ++ct) {
                float pn  = pads[ct * 16 + c];
                int   kgi = k0 + ct * 16 + c;
                #pragma unroll
                for (int r = 0; r < 4; ++r) {
                    float lg = sc[ct][r] * 0.125f + pn;
                    if (kgi > qgBase + r) lg -= NEG_BIG;
                    float wv = __expf(lg - m[r]) * linv[r];
                    Wf[16 * w + 4 * g + r][ct * 16 + c] = wv;
                }
            }
            __syncthreads();

            #pragma unroll
            for (int i = 0; i < 4; ++i) {
                int f4 = i * 256 + tid;
                int r  = f4 >> 4;
                int c4 = (f4 & 15) * 4;
                float4 wv = *(const float4*)&Wf[r][c4];
                *(float4*)(wbase + (size_t)r * S_LEN + c4) = wv;
            }

            #pragma unroll
            for (int ks = 0; ks < 2; ++ks) {
                float4 f0 = *(const float4*)&Wf[16 * w + c][ks * 32 + 8 * g];
                float4 f1 = *(const float4*)&Wf[16 * w + c][ks * 32 + 8 * g + 4];
                bf16x8 wa;
                wa[0]=(bf16_t)f0.x; wa[1]=(bf16_t)f0.y; wa[2]=(bf16_t)f0.z; wa[3]=(bf16_t)f0.w;
                wa[4]=(bf16_t)f1.x; wa[5]=(bf16_t)f1.y; wa[6]=(bf16_t)f1.z; wa[7]=(bf16_t)f1.w;
                #pragma unroll
                for (int dt = 0; dt < 4; ++dt) {
                    bf16x8 vb = *(const bf16x8*)&VT[dt * 16 + c][ks * 32 + 8 * g];
                    o[dt] = __builtin_amdgcn_mfma_f32_16x16x32_bf16(wa, vb, o[dt], 0, 0, 0);
                }
            }
            __syncthreads();
        } else {
            const float4 z = {0.f, 0.f, 0.f, 0.f};
            #pragma unroll
            for (int i = 0; i < 4; ++i) {
                int f4 = i * 256 + tid;
                int r  = f4 >> 4;
                int c4 = (f4 & 15) * 4;
                *(float4*)(wbase + (size_t)r * S_LEN + c4) = z;
            }
        }
    }

    #pragma unroll
    for (int dt = 0; dt < 4; ++dt)
        #pragma unroll
        for (int r = 0; r < 4; ++r)
            Og[((size_t)b * S_LEN + (q0 + 16 * w + 4 * g + r)) * D_DIM + dt * 16 + c] = o[dt][r];
}

extern "C" void kernel_launch(void* const* d_in, const int* in_sizes, int n_in,
                              void* d_out, int out_size, void* d_ws, size_t ws_size,
                              hipStream_t stream) {
    const float* q   = (const float*)d_in[0];
    const float* k   = (const float*)d_in[1];
    const float* v   = (const float*)d_in[2];
    const float* pad = (const float*)d_in[3];

    float* out  = (float*)d_out;
    float* ctx  = out;
    float* attw = out + (size_t)8 * 4096 * 64;
    float* ws   = (float*)d_ws;

    if (ws_size >= (size_t)WS_FLOATS_NEEDED * 4) {
        hipLaunchKernelGGL(sdpa_stats, dim3(4096), dim3(256), 0, stream, q, k, pad, ws, ctx);
        hipLaunchKernelGGL(sdpa_wpv,   dim3(4096), dim3(256), 0, stream, q, k, v, pad, attw, ws, ctx);
    } else {
        hipLaunchKernelGGL(sdpa_fused, dim3(512), dim3(256), 0, stream, q, k, v, pad, ctx, attw);
    }
}